// Round 2
// baseline (399.729 us; speedup 1.0000x reference)
//
#include <hip/hip_runtime.h>

typedef float        f32x4  __attribute__((ext_vector_type(4)));
typedef __bf16       bf16x8 __attribute__((ext_vector_type(8)));
typedef unsigned int u32x4  __attribute__((ext_vector_type(4)));
typedef unsigned short u16;

#define MFMA16(a,b,c) __builtin_amdgcn_mfma_f32_16x16x32_bf16((a),(b),(c),0,0,0)

// ---- fp32 -> bf16 hi/lo split (RNE both) : x ~= hi + lo, rel err ~2^-17 ----
__device__ __forceinline__ unsigned bf_rnd(float x) {
    unsigned u = __float_as_uint(x);
    return (u + 0x7FFFu + ((u >> 16) & 1u)) & 0xFFFF0000u;
}
__device__ __forceinline__ void split_bf(float x, unsigned &h, unsigned &l) {
    unsigned hr = bf_rnd(x);
    h = hr >> 16;
    float lo = x - __uint_as_float(hr);
    l = bf_rnd(lo) >> 16;
}
// pack 8 consecutive f32 (two f32x4) -> hi bf16x8, lo bf16x8 (memory order)
__device__ __forceinline__ void split8(const f32x4 a, const f32x4 b, bf16x8 &hv, bf16x8 &lv) {
    u32x4 hp, lp;
    unsigned h0,l0,h1,l1;
    split_bf(a[0],h0,l0); split_bf(a[1],h1,l1); hp[0]=h0|(h1<<16); lp[0]=l0|(l1<<16);
    split_bf(a[2],h0,l0); split_bf(a[3],h1,l1); hp[1]=h0|(h1<<16); lp[1]=l0|(l1<<16);
    split_bf(b[0],h0,l0); split_bf(b[1],h1,l1); hp[2]=h0|(h1<<16); lp[2]=l0|(l1<<16);
    split_bf(b[2],h0,l0); split_bf(b[3],h1,l1); hp[3]=h0|(h1<<16); lp[3]=l0|(l1<<16);
    hv = __builtin_bit_cast(bf16x8, hp);
    lv = __builtin_bit_cast(bf16x8, lp);
}
__device__ __forceinline__ bf16x8 ld16(const u16* p) {
    return __builtin_bit_cast(bf16x8, *(const u32x4*)p);
}

// =====================================================================
// K0: pre-transpose + pre-split all weights into ws (bf16 hi/lo arrays).
// WeT[f][e] (128x128), WrT[h][k] (256x384), W0T/W1T[h][k] (256x256).
// 960 blocks x 256 = 245760 threads = one element each.
// =====================================================================
__global__ __launch_bounds__(256) void k_prep(
    const float* __restrict__ We, const float* __restrict__ Wr,
    const float* __restrict__ W0, const float* __restrict__ W1,
    u16* __restrict__ WeTh, u16* __restrict__ WeTl,
    u16* __restrict__ WrTh, u16* __restrict__ WrTl,
    u16* __restrict__ W0Th, u16* __restrict__ W0Tl,
    u16* __restrict__ W1Th, u16* __restrict__ W1Tl)
{
    int t = blockIdx.x * 256 + threadIdx.x;
    float v; u16 *dh, *dl; int dst;
    if (t < 16384) {                       // We 128x128 -> WeT
        int f = t & 127, e = t >> 7;
        v = We[e*128 + f]; dst = f*128 + e; dh = WeTh; dl = WeTl;
    } else if (t < 16384 + 98304) {        // Wr 384x256 -> WrT
        int u = t - 16384; int h = u & 255, k = u >> 8;
        v = Wr[k*256 + h]; dst = h*384 + k; dh = WrTh; dl = WrTl;
    } else if (t < 16384 + 98304 + 65536) {// W0 256x256 -> W0T
        int u = t - 16384 - 98304; int h = u & 255, k = u >> 8;
        v = W0[k*256 + h]; dst = h*256 + k; dh = W0Th; dl = W0Tl;
    } else {                               // W1
        int u = t - 16384 - 98304 - 65536; int h = u & 255, k = u >> 8;
        v = W1[k*256 + h]; dst = h*256 + k; dh = W1Th; dl = W1Tl;
    }
    unsigned hh, ll; split_bf(v, hh, ll);
    dh[dst] = (u16)hh; dl[dst] = (u16)ll;
}

// =====================================================================
// K1: fused edge-mapper + msg_e partial reduction. Barrier-free, LDS-free.
// Block = 512 thr (8 waves, 4 j-groups x 2 f-groups), grid 256 = 16 b x 16
// chunks of 8 i-slabs. Per slab: E frags direct from global (f32 -> hi/lo
// in reg), W frags direct from pre-split WeT (L2). Next slab register-
// prefetched; no __syncthreads anywhere -> no vmcnt(0) drain.
// =====================================================================
__global__ __launch_bounds__(512, 2) void k_edge(
    const float* __restrict__ E, const float* __restrict__ A,
    const u16* __restrict__ WeTh, const u16* __restrict__ WeTl,
    const float* __restrict__ be, float* __restrict__ part)
{
    const int tid  = threadIdx.x;
    const int lane = tid & 63;
    const int wid  = tid >> 6;
    const int wm   = (wid >> 1) << 5;    // 0,32,64,96 (j)
    const int wn   = (wid & 1)  << 6;    // 0,64       (f)
    const int lrow = lane & 15;
    const int lk   = lane >> 4;          // k-group 0..3
    const int b    = blockIdx.x >> 4;
    const int c    = blockIdx.x & 15;
    const int i0   = c << 3;

    float ber[4];
    #pragma unroll
    for (int n = 0; n < 4; ++n) ber[n] = be[wn + n*16 + lrow];

    const float* Eb = E + (size_t)(b*128 + i0) * 16384;

    f32x4 eb[16];    // slab E data: [m(2) x k(4)] x 2 f32x4 (8 elems along e)
    {
        const float* Es = Eb;
        #pragma unroll
        for (int m = 0; m < 2; ++m)
            #pragma unroll
            for (int k = 0; k < 4; ++k) {
                const float* p = Es + (wm + m*16 + lrow)*128 + k*32 + lk*8;
                eb[(m*4+k)*2+0] = *(const f32x4*)p;
                eb[(m*4+k)*2+1] = *(const f32x4*)(p+4);
            }
    }

    f32x4 P[2][4] = {};   // msg_e partials, live whole loop

    for (int s = 0; s < 8; ++s) {
        // convert slab -> bf16 hi/lo fragments (frees eb for prefetch)
        bf16x8 ehf[8], elf[8];     // [m*4+k]
        #pragma unroll
        for (int q = 0; q < 8; ++q)
            split8(eb[q*2+0], eb[q*2+1], ehf[q], elf[q]);

        if (s < 7) {   // issue next-slab loads; covered by MFMA phase below
            const float* Es = Eb + (size_t)(s+1)*16384;
            #pragma unroll
            for (int m = 0; m < 2; ++m)
                #pragma unroll
                for (int k = 0; k < 4; ++k) {
                    const float* p = Es + (wm + m*16 + lrow)*128 + k*32 + lk*8;
                    eb[(m*4+k)*2+0] = *(const f32x4*)p;
                    eb[(m*4+k)*2+1] = *(const f32x4*)(p+4);
                }
        }

        // Em = E @ We  (3-pass hi/lo), W frags streamed from L2
        f32x4 em[2][4] = {};
        #pragma unroll
        for (int k = 0; k < 4; ++k) {
            bf16x8 wh[4], wl[4];
            #pragma unroll
            for (int n = 0; n < 4; ++n) {
                const int off = (wn + n*16 + lrow)*128 + k*32 + lk*8;
                wh[n] = ld16(WeTh + off);
                wl[n] = ld16(WeTl + off);
            }
            #pragma unroll
            for (int m = 0; m < 2; ++m)
                #pragma unroll
                for (int n = 0; n < 4; ++n) {
                    em[m][n] = MFMA16(ehf[m*4+k], wh[n], em[m][n]);
                    em[m][n] = MFMA16(ehf[m*4+k], wl[n], em[m][n]);
                    em[m][n] = MFMA16(elf[m*4+k], wh[n], em[m][n]);
                }
        }

        // P += A[b,i,j] * relu(em + be)
        const int i = i0 + s;
        #pragma unroll
        for (int m = 0; m < 2; ++m) {
            const f32x4 a4 = *(const f32x4*)(A + (size_t)(b*128 + i)*128 + wm + m*16 + lk*4);
            #pragma unroll
            for (int n = 0; n < 4; ++n)
                #pragma unroll
                for (int r = 0; r < 4; ++r) {
                    float v = fmaxf(em[m][n][r] + ber[n], 0.0f);
                    P[m][n][r] += a4[r] * v;
                }
        }
    }

    // write partial tile part[block][j][f]
    float* op = part + (size_t)blockIdx.x * 16384;
    #pragma unroll
    for (int m = 0; m < 2; ++m)
        #pragma unroll
        for (int r = 0; r < 4; ++r) {
            const int j = wm + m*16 + lk*4 + r;
            #pragma unroll
            for (int n = 0; n < 4; ++n)
                op[j*128 + wn + n*16 + lrow] = P[m][n][r];
        }
}

// =====================================================================
// K2 (role-split): blocks 0..1023  -> msg_e = sum of 16 partials
//                  blocks 1024..1279 -> msg_x = A^T X (per b, 8 j-rows)
// Both write msg pre-split as bf16 hi/lo [2048][384] (x-part | e-part).
// =====================================================================
__global__ __launch_bounds__(256) void k_msg(
    const float* __restrict__ A, const float* __restrict__ X,
    const float* __restrict__ part,
    u16* __restrict__ msg_h, u16* __restrict__ msg_l)
{
    const int bid = blockIdx.x;
    const int tid = threadIdx.x;
    __shared__ float sAt[128*8];

    if (bid < 1024) {
        const int b = bid >> 6, jp = bid & 63;
        const int j = jp*2 + (tid >> 7), f = tid & 127;
        const float* p = part + (size_t)b*16*16384 + j*128 + f;
        float s = 0.f;
        #pragma unroll
        for (int cc = 0; cc < 16; ++cc) s += p[(size_t)cc*16384];
        unsigned hh, ll; split_bf(s, hh, ll);
        const size_t o = (size_t)(b*128 + j)*384 + 256 + f;
        msg_h[o] = (u16)hh; msg_l[o] = (u16)ll;
    } else {
        const int idx = bid - 1024;
        const int b = idx >> 4, jt = idx & 15, j0 = jt << 3;
        #pragma unroll
        for (int q = 0; q < 4; ++q) {
            const int e = tid + q*256;          // 0..1023 = 128 i x 8 j
            sAt[e] = A[(size_t)(b*128 + (e >> 3))*128 + j0 + (e & 7)];
        }
        __syncthreads();
        const int h = tid;
        float acc[8] = {};
        const float* Xb = X + (size_t)b*128*256 + h;
        #pragma unroll 4
        for (int i = 0; i < 128; ++i) {
            const float x = Xb[(size_t)i*256];
            #pragma unroll
            for (int jj = 0; jj < 8; ++jj) acc[jj] += sAt[i*8 + jj] * x;
        }
        #pragma unroll
        for (int jj = 0; jj < 8; ++jj) {
            unsigned hh, ll; split_bf(acc[jj], hh, ll);
            const size_t o = (size_t)(b*128 + j0 + jj)*384 + h;
            msg_h[o] = (u16)hh; msg_l[o] = (u16)ll;
        }
    }
}

// =====================================================================
// K3/K4/K5: tail GEMM, pure-register MFMA (inputs already split bf16).
// out(2048x256) = [ (1+eps)*res + ] relu(In(2048xKT) @ W(KTx256) + bias)
// grid (64,4): 32-row x 64-col tiles; 4 waves 2x2 (m=1, n=2 of 16x16).
// =====================================================================
template<int KT, bool RES, bool F32OUT>
__global__ __launch_bounds__(256) void k_tail(
    const u16* __restrict__ Ah, const u16* __restrict__ Al,
    const u16* __restrict__ Bh, const u16* __restrict__ Bl,
    const float* __restrict__ bias, const float* __restrict__ res,
    const float* __restrict__ epsp,
    float* __restrict__ outf, u16* __restrict__ oh, u16* __restrict__ ol)
{
    const int tid  = threadIdx.x;
    const int lane = tid & 63;
    const int wid  = tid >> 6;
    const int lrow = lane & 15;
    const int lk   = lane >> 4;
    const int wm   = (wid >> 1) << 4;    // 0/16
    const int wn   = (wid & 1)  << 5;    // 0/32
    const int r0   = blockIdx.x << 5;
    const int h0   = blockIdx.y << 6;

    const int arow = r0 + wm + lrow;
    const u16* pah = Ah + (size_t)arow*KT + lk*8;
    const u16* pal = Al + (size_t)arow*KT + lk*8;
    const int c0 = h0 + wn + lrow;
    const u16* pb0h = Bh + (size_t)c0*KT + lk*8;
    const u16* pb0l = Bl + (size_t)c0*KT + lk*8;
    const u16* pb1h = pb0h + 16*KT;
    const u16* pb1l = pb0l + 16*KT;

    f32x4 P[2] = {};
    #pragma unroll
    for (int ks = 0; ks < KT/32; ++ks) {
        const bf16x8 ah = ld16(pah + ks*32);
        const bf16x8 al = ld16(pal + ks*32);
        const bf16x8 b0h = ld16(pb0h + ks*32), b0l = ld16(pb0l + ks*32);
        const bf16x8 b1h = ld16(pb1h + ks*32), b1l = ld16(pb1l + ks*32);
        P[0] = MFMA16(ah, b0h, P[0]);
        P[0] = MFMA16(ah, b0l, P[0]);
        P[0] = MFMA16(al, b0h, P[0]);
        P[1] = MFMA16(ah, b1h, P[1]);
        P[1] = MFMA16(ah, b1l, P[1]);
        P[1] = MFMA16(al, b1h, P[1]);
    }

    const float eps = RES ? epsp[0] : 0.f;
    #pragma unroll
    for (int n = 0; n < 2; ++n) {
        const int col = h0 + wn + n*16 + lrow;
        const float bv = bias[col];
        #pragma unroll
        for (int e = 0; e < 4; ++e) {
            const int r = r0 + wm + lk*4 + e;
            float v = fmaxf(P[n][e] + bv, 0.f);
            if (RES) v += (1.f + eps) * res[(size_t)r*256 + col];
            if (F32OUT) {
                outf[(size_t)r*256 + col] = v;
            } else {
                unsigned hh, ll; split_bf(v, hh, ll);
                oh[(size_t)r*256 + col] = (u16)hh;
                ol[(size_t)r*256 + col] = (u16)ll;
            }
        }
    }
}

extern "C" void kernel_launch(void* const* d_in, const int* in_sizes, int n_in,
                              void* d_out, int out_size, void* d_ws, size_t ws_size,
                              hipStream_t stream)
{
    const float* X   = (const float*)d_in[0];
    const float* E   = (const float*)d_in[1];
    const float* A   = (const float*)d_in[2];
    const float* eps = (const float*)d_in[3];
    const float* We  = (const float*)d_in[4];
    const float* be  = (const float*)d_in[5];
    const float* Wr  = (const float*)d_in[6];
    const float* br  = (const float*)d_in[7];
    const float* W0  = (const float*)d_in[8];
    const float* b0  = (const float*)d_in[9];
    const float* W1  = (const float*)d_in[10];
    const float* b1  = (const float*)d_in[11];
    float* out = (float*)d_out;

    // ws layout (u16 units, all 16B-aligned)
    u16* w = (u16*)d_ws;
    u16* WeTh = w;              u16* WeTl = WeTh + 16384;
    u16* WrTh = WeTl + 16384;   u16* WrTl = WrTh + 98304;
    u16* W0Th = WrTl + 98304;   u16* W0Tl = W0Th + 65536;
    u16* W1Th = W0Tl + 65536;   u16* W1Tl = W1Th + 65536;
    u16* msg_h = W1Tl + 65536;  u16* msg_l = msg_h + 786432;
    u16* o1h = msg_l + 786432;  u16* o1l = o1h + 524288;
    u16* o2h = o1l + 524288;    u16* o2l = o2h + 524288;
    float* part = (float*)(o2l + 524288);   // 256 * 16384 f32 = 16 MB

    k_prep<<<960, 256, 0, stream>>>(We, Wr, W0, W1,
        WeTh, WeTl, WrTh, WrTl, W0Th, W0Tl, W1Th, W1Tl);
    k_edge<<<256, 512, 0, stream>>>(E, A, WeTh, WeTl, be, part);
    k_msg<<<1280, 256, 0, stream>>>(A, X, part, msg_h, msg_l);
    k_tail<384, true , false><<<dim3(64,4), 256, 0, stream>>>(
        msg_h, msg_l, WrTh, WrTl, br, X, eps, nullptr, o1h, o1l);
    k_tail<256, false, false><<<dim3(64,4), 256, 0, stream>>>(
        o1h, o1l, W0Th, W0Tl, b0, nullptr, nullptr, nullptr, o2h, o2l);
    k_tail<256, false, true ><<<dim3(64,4), 256, 0, stream>>>(
        o2h, o2l, W1Th, W1Tl, b1, nullptr, nullptr, out, nullptr, nullptr);
}

// Round 3
// 282.366 us; speedup vs baseline: 1.4156x; 1.4156x over previous
//
#include <hip/hip_runtime.h>

typedef float        f32x4  __attribute__((ext_vector_type(4)));
typedef __bf16       bf16x8 __attribute__((ext_vector_type(8)));
typedef unsigned int u32x4  __attribute__((ext_vector_type(4)));
typedef unsigned short u16;

#define MFMA16(a,b,c) __builtin_amdgcn_mfma_f32_16x16x32_bf16((a),(b),(c),0,0,0)

typedef __attribute__((address_space(3))) unsigned int       as3_u32;
typedef __attribute__((address_space(1))) const unsigned int as1_u32;
__device__ __forceinline__ void gld16(const float* g, float* l) {
    __builtin_amdgcn_global_load_lds((as1_u32*)g, (as3_u32*)l, 16, 0, 0);
}

// ---- fp32 -> bf16 hi/lo split. hi = truncation, lo = RNE(x-hi) ----
__device__ __forceinline__ unsigned bf_rnd(float x) {
    unsigned u = __float_as_uint(x);
    return (u + 0x7FFFu + ((u >> 16) & 1u)) & 0xFFFF0000u;
}
__device__ __forceinline__ void split_bf(float x, unsigned &h, unsigned &l) {
    unsigned hr = bf_rnd(x);
    h = hr >> 16;
    float lo = x - __uint_as_float(hr);
    l = bf_rnd(lo) >> 16;
}
// quick split of 8 f32 (hi=trunc is exact-compensated by lo)
__device__ __forceinline__ void split8q(const f32x4 a, const f32x4 b, bf16x8 &hv, bf16x8 &lv) {
    u32x4 hp, lp;
    #pragma unroll
    for (int i = 0; i < 2; ++i) {
        float x0 = (i ? b : a)[0], x1 = (i ? b : a)[1], x2 = (i ? b : a)[2], x3 = (i ? b : a)[3];
        unsigned h0 = __float_as_uint(x0) & 0xFFFF0000u;
        unsigned h1 = __float_as_uint(x1) & 0xFFFF0000u;
        unsigned h2 = __float_as_uint(x2) & 0xFFFF0000u;
        unsigned h3 = __float_as_uint(x3) & 0xFFFF0000u;
        unsigned l0 = bf_rnd(x0 - __uint_as_float(h0));
        unsigned l1 = bf_rnd(x1 - __uint_as_float(h1));
        unsigned l2 = bf_rnd(x2 - __uint_as_float(h2));
        unsigned l3 = bf_rnd(x3 - __uint_as_float(h3));
        hp[i*2+0] = (h0 >> 16) | h1;  lp[i*2+0] = (l0 >> 16) | l1;
        hp[i*2+1] = (h2 >> 16) | h3;  lp[i*2+1] = (l2 >> 16) | l3;
    }
    hv = __builtin_bit_cast(bf16x8, hp);
    lv = __builtin_bit_cast(bf16x8, lp);
}
__device__ __forceinline__ bf16x8 ld16(const u16* p) {
    return __builtin_bit_cast(bf16x8, *(const u32x4*)p);
}

// =====================================================================
// K0: pre-transpose + pre-split weights (bf16 hi/lo) into ws.
// =====================================================================
__global__ __launch_bounds__(256) void k_prep(
    const float* __restrict__ We, const float* __restrict__ Wr,
    const float* __restrict__ W0, const float* __restrict__ W1,
    u16* __restrict__ WeTh, u16* __restrict__ WeTl,
    u16* __restrict__ WrTh, u16* __restrict__ WrTl,
    u16* __restrict__ W0Th, u16* __restrict__ W0Tl,
    u16* __restrict__ W1Th, u16* __restrict__ W1Tl)
{
    int t = blockIdx.x * 256 + threadIdx.x;
    float v; u16 *dh, *dl; int dst;
    if (t < 16384) {
        int f = t & 127, e = t >> 7;
        v = We[e*128 + f]; dst = f*128 + e; dh = WeTh; dl = WeTl;
    } else if (t < 16384 + 98304) {
        int u = t - 16384; int h = u & 255, k = u >> 8;
        v = Wr[k*256 + h]; dst = h*384 + k; dh = WrTh; dl = WrTl;
    } else if (t < 16384 + 98304 + 65536) {
        int u = t - 16384 - 98304; int h = u & 255, k = u >> 8;
        v = W0[k*256 + h]; dst = h*256 + k; dh = W0Th; dl = W0Tl;
    } else {
        int u = t - 16384 - 98304 - 65536; int h = u & 255, k = u >> 8;
        v = W1[k*256 + h]; dst = h*256 + k; dh = W1Th; dl = W1Tl;
    }
    unsigned hh, ll; split_bf(v, hh, ll);
    dh[dst] = (u16)hh; dl[dst] = (u16)ll;
}

// =====================================================================
// K1: fused edge-mapper + msg_e partial reduction.
// Grid 512 = 16b x 16c(8 i each) x 2 j-halves. Block 256 thr (4 waves,
// 2j x 2f), 64 KB LDS (f32 E half-tile, double-buffered) -> 2 blocks/CU.
// W(hi/lo) resident in 128 VGPRs; E via global_load_lds w/ source-side
// XOR swizzle; one __syncthreads per slab, stage issued after barrier.
// =====================================================================
__device__ __forceinline__ void stage_slab(const float* __restrict__ Eslab,
                                           float* buf, int tid) {
    const int w = tid >> 6, l = tid & 63;
    #pragma unroll
    for (int r = 0; r < 8; ++r) {
        const int q   = (r << 2) + w;            // 1KB chunk, wave-uniform
        const int row = (q << 1) + (l >> 5);     // 0..63
        const int cof = (((l & 31) ^ (row & 7)) << 4);   // swizzled byte col
        gld16(Eslab + row*128 + (cof >> 2), buf + (q << 8));
    }
}

__global__ __launch_bounds__(256) __attribute__((amdgpu_waves_per_eu(2, 2)))
void k_edge(
    const float* __restrict__ E, const float* __restrict__ A,
    const u16* __restrict__ WeTh, const u16* __restrict__ WeTl,
    const float* __restrict__ be, float* __restrict__ part)
{
    __shared__ __align__(16) float sE[2][64*128];   // 2 x 32 KB

    const int tid  = threadIdx.x;
    const int lane = tid & 63;
    const int wv   = tid >> 6;
    const int lrow = lane & 15;
    const int lk   = lane >> 4;
    const int wm   = (wv >> 1) << 5;   // j-offset in half: 0/32
    const int wn   = (wv & 1)  << 6;   // f-offset: 0/64
    const int bid  = blockIdx.x;
    const int jh   = bid & 1;
    const int c    = (bid >> 1) & 15;
    const int b    = bid >> 5;
    const int i0   = c << 3;
    const int j0   = jh << 6;

    // W fragments resident in registers for the whole kernel (128 VGPR)
    bf16x8 wh[4][4], wl[4][4];
    #pragma unroll
    for (int n = 0; n < 4; ++n)
        #pragma unroll
        for (int k = 0; k < 4; ++k) {
            const int off = (wn + n*16 + lrow)*128 + k*32 + lk*8;
            wh[n][k] = ld16(WeTh + off);
            wl[n][k] = ld16(WeTl + off);
        }
    float ber[4];
    #pragma unroll
    for (int n = 0; n < 4; ++n) ber[n] = be[wn + n*16 + lrow];

    const float* Eb = E + ((size_t)((b*128 + i0)*128 + j0)) * 128;
    stage_slab(Eb, sE[0], tid);   // prologue: slab 0

    f32x4 P[2][4] = {};

    for (int s = 0; s < 8; ++s) {
        __syncthreads();   // slab-s data landed; prev buffer reads all done
        if (s < 7)         // flies under the MFMA phase below
            stage_slab(Eb + (size_t)(s+1)*16384, sE[(s+1) & 1], tid);

        const char* buf = (const char*)sE[s & 1];
        f32x4 em[2][4] = {};
        #pragma unroll
        for (int k = 0; k < 4; ++k) {
            #pragma unroll
            for (int m = 0; m < 2; ++m) {
                const int jr = wm + m*16 + lrow;
                const int cb = k*128 + lk*32;
                const int sw = (jr & 7) << 4;
                const f32x4 e0 = *(const f32x4*)(buf + jr*512 + ((cb +  0) ^ sw));
                const f32x4 e1 = *(const f32x4*)(buf + jr*512 + ((cb + 16) ^ sw));
                bf16x8 eh, el; split8q(e0, e1, eh, el);
                #pragma unroll
                for (int n = 0; n < 4; ++n) {
                    em[m][n] = MFMA16(eh, wh[n][k], em[m][n]);
                    em[m][n] = MFMA16(eh, wl[n][k], em[m][n]);
                    em[m][n] = MFMA16(el, wh[n][k], em[m][n]);
                }
            }
        }

        // P += A[b, i0+s, j] * relu(em + be)
        const float* Arow = A + (size_t)(b*128 + i0 + s)*128 + j0;
        #pragma unroll
        for (int m = 0; m < 2; ++m) {
            const f32x4 a4 = *(const f32x4*)(Arow + wm + m*16 + lk*4);
            #pragma unroll
            for (int n = 0; n < 4; ++n)
                #pragma unroll
                for (int r = 0; r < 4; ++r) {
                    float v = fmaxf(em[m][n][r] + ber[n], 0.0f);
                    P[m][n][r] += a4[r] * v;
                }
        }
    }

    // partial tile: part[bid][64][128]
    float* op = part + (size_t)bid * 8192;
    #pragma unroll
    for (int m = 0; m < 2; ++m)
        #pragma unroll
        for (int r = 0; r < 4; ++r) {
            const int j = wm + m*16 + lk*4 + r;
            #pragma unroll
            for (int n = 0; n < 4; ++n)
                op[j*128 + wn + n*16 + lrow] = P[m][n][r];
        }
}

// =====================================================================
// K2 (role-split, grid 512): blocks 0..255 reduce msg_e partials,
// blocks 256..511 compute msg_x = A^T X. Output msg pre-split bf16 hi/lo.
// =====================================================================
__global__ __launch_bounds__(256) void k_msg(
    const float* __restrict__ A, const float* __restrict__ X,
    const float* __restrict__ part,
    u16* __restrict__ msg_h, u16* __restrict__ msg_l)
{
    const int bid = blockIdx.x;
    const int tid = threadIdx.x;
    __shared__ float sAt[128*8];

    if (bid < 256) {
        const int b = bid >> 4, jt = bid & 15;
        #pragma unroll
        for (int q = 0; q < 4; ++q) {
            const int e   = (q << 8) + tid;
            const int row = jt*8 + (e >> 7);
            const int f   = e & 127;
            const int jhh = row >> 6, rl = row & 63;
            const float* p = part + ((size_t)(b*32 + jhh))*8192 + rl*128 + f;
            float ssum = 0.f;
            #pragma unroll
            for (int cc = 0; cc < 16; ++cc) ssum += p[(size_t)cc*16384];
            unsigned hh, ll; split_bf(ssum, hh, ll);
            const size_t o = (size_t)(b*128 + row)*384 + 256 + f;
            msg_h[o] = (u16)hh; msg_l[o] = (u16)ll;
        }
    } else {
        const int idx = bid - 256;
        const int b = idx >> 4, jt = idx & 15, j0 = jt << 3;
        #pragma unroll
        for (int q = 0; q < 4; ++q) {
            const int e = tid + q*256;           // 128 i x 8 j
            sAt[e] = A[(size_t)(b*128 + (e >> 3))*128 + j0 + (e & 7)];
        }
        __syncthreads();
        const int h = tid;
        float acc[8] = {};
        const float* Xb = X + (size_t)b*32768 + h;
        #pragma unroll 2
        for (int i = 0; i < 128; ++i) {
            const float x  = Xb[(size_t)i*256];
            const f32x4 a0 = *(const f32x4*)(sAt + i*8);
            const f32x4 a1 = *(const f32x4*)(sAt + i*8 + 4);
            acc[0] += a0[0]*x; acc[1] += a0[1]*x; acc[2] += a0[2]*x; acc[3] += a0[3]*x;
            acc[4] += a1[0]*x; acc[5] += a1[1]*x; acc[6] += a1[2]*x; acc[7] += a1[3]*x;
        }
        #pragma unroll
        for (int jj = 0; jj < 8; ++jj) {
            unsigned hh, ll; split_bf(acc[jj], hh, ll);
            const size_t o = (size_t)(b*128 + j0 + jj)*384 + h;
            msg_h[o] = (u16)hh; msg_l[o] = (u16)ll;
        }
    }
}

// =====================================================================
// K3/K4/K5: tail GEMM, pure-register MFMA (inputs pre-split bf16).
// out(2048x256) = [ (1+eps)*res + ] relu(In(2048xKT) @ W(KTx256) + bias)
// =====================================================================
template<int KT, bool RES, bool F32OUT>
__global__ __launch_bounds__(256) void k_tail(
    const u16* __restrict__ Ah, const u16* __restrict__ Al,
    const u16* __restrict__ Bh, const u16* __restrict__ Bl,
    const float* __restrict__ bias, const float* __restrict__ res,
    const float* __restrict__ epsp,
    float* __restrict__ outf, u16* __restrict__ oh, u16* __restrict__ ol)
{
    const int tid  = threadIdx.x;
    const int lane = tid & 63;
    const int wid  = tid >> 6;
    const int lrow = lane & 15;
    const int lk   = lane >> 4;
    const int wm   = (wid >> 1) << 4;
    const int wn   = (wid & 1)  << 5;
    const int r0   = blockIdx.x << 5;
    const int h0   = blockIdx.y << 6;

    const int arow = r0 + wm + lrow;
    const u16* pah = Ah + (size_t)arow*KT + lk*8;
    const u16* pal = Al + (size_t)arow*KT + lk*8;
    const int c0 = h0 + wn + lrow;
    const u16* pb0h = Bh + (size_t)c0*KT + lk*8;
    const u16* pb0l = Bl + (size_t)c0*KT + lk*8;
    const u16* pb1h = pb0h + 16*KT;
    const u16* pb1l = pb0l + 16*KT;

    f32x4 P[2] = {};
    #pragma unroll
    for (int ks = 0; ks < KT/32; ++ks) {
        const bf16x8 ah  = ld16(pah  + ks*32);
        const bf16x8 al  = ld16(pal  + ks*32);
        const bf16x8 b0h = ld16(pb0h + ks*32), b0l = ld16(pb0l + ks*32);
        const bf16x8 b1h = ld16(pb1h + ks*32), b1l = ld16(pb1l + ks*32);
        P[0] = MFMA16(ah, b0h, P[0]);
        P[0] = MFMA16(ah, b0l, P[0]);
        P[0] = MFMA16(al, b0h, P[0]);
        P[1] = MFMA16(ah, b1h, P[1]);
        P[1] = MFMA16(ah, b1l, P[1]);
        P[1] = MFMA16(al, b1h, P[1]);
    }

    const float eps = RES ? epsp[0] : 0.f;
    #pragma unroll
    for (int n = 0; n < 2; ++n) {
        const int col = h0 + wn + n*16 + lrow;
        const float bv = bias[col];
        #pragma unroll
        for (int e = 0; e < 4; ++e) {
            const int r = r0 + wm + lk*4 + e;
            float v = fmaxf(P[n][e] + bv, 0.f);
            if (RES) v += (1.f + eps) * res[(size_t)r*256 + col];
            if (F32OUT) {
                outf[(size_t)r*256 + col] = v;
            } else {
                unsigned hh, ll; split_bf(v, hh, ll);
                oh[(size_t)r*256 + col] = (u16)hh;
                ol[(size_t)r*256 + col] = (u16)ll;
            }
        }
    }
}

extern "C" void kernel_launch(void* const* d_in, const int* in_sizes, int n_in,
                              void* d_out, int out_size, void* d_ws, size_t ws_size,
                              hipStream_t stream)
{
    const float* X   = (const float*)d_in[0];
    const float* E   = (const float*)d_in[1];
    const float* A   = (const float*)d_in[2];
    const float* eps = (const float*)d_in[3];
    const float* We  = (const float*)d_in[4];
    const float* be  = (const float*)d_in[5];
    const float* Wr  = (const float*)d_in[6];
    const float* br  = (const float*)d_in[7];
    const float* W0  = (const float*)d_in[8];
    const float* b0  = (const float*)d_in[9];
    const float* W1  = (const float*)d_in[10];
    const float* b1  = (const float*)d_in[11];
    float* out = (float*)d_out;

    u16* w = (u16*)d_ws;
    u16* WeTh = w;              u16* WeTl = WeTh + 16384;
    u16* WrTh = WeTl + 16384;   u16* WrTl = WrTh + 98304;
    u16* W0Th = WrTl + 98304;   u16* W0Tl = W0Th + 65536;
    u16* W1Th = W0Tl + 65536;   u16* W1Tl = W1Th + 65536;
    u16* msg_h = W1Tl + 65536;  u16* msg_l = msg_h + 786432;
    u16* o1h = msg_l + 786432;  u16* o1l = o1h + 524288;
    u16* o2h = o1l + 524288;    u16* o2l = o2h + 524288;
    float* part = (float*)(o2l + 524288);   // 512 * 8192 f32 = 16 MB

    k_prep<<<960, 256, 0, stream>>>(We, Wr, W0, W1,
        WeTh, WeTl, WrTh, WrTl, W0Th, W0Tl, W1Th, W1Tl);
    k_edge<<<512, 256, 0, stream>>>(E, A, WeTh, WeTl, be, part);
    k_msg<<<512, 256, 0, stream>>>(A, X, part, msg_h, msg_l);
    k_tail<384, true , false><<<dim3(64,4), 256, 0, stream>>>(
        msg_h, msg_l, WrTh, WrTl, br, X, eps, nullptr, o1h, o1l);
    k_tail<256, false, false><<<dim3(64,4), 256, 0, stream>>>(
        o1h, o1l, W0Th, W0Tl, b0, nullptr, nullptr, nullptr, o2h, o2l);
    k_tail<256, false, true ><<<dim3(64,4), 256, 0, stream>>>(
        o2h, o2l, W1Th, W1Tl, b1, nullptr, nullptr, out, nullptr, nullptr);
}

// Round 5
// 267.439 us; speedup vs baseline: 1.4947x; 1.0558x over previous
//
#include <hip/hip_runtime.h>

typedef float        f32x4  __attribute__((ext_vector_type(4)));
typedef __bf16       bf16x8 __attribute__((ext_vector_type(8)));
typedef unsigned int u32x4  __attribute__((ext_vector_type(4)));
typedef unsigned short u16;

#define MFMA16(a,b,c) __builtin_amdgcn_mfma_f32_16x16x32_bf16((a),(b),(c),0,0,0)

typedef __attribute__((address_space(3))) unsigned int       as3_u32;
typedef __attribute__((address_space(1))) const unsigned int as1_u32;
__device__ __forceinline__ void gld16(const float* g, float* l) {
    __builtin_amdgcn_global_load_lds((as1_u32*)g, (as3_u32*)l, 16, 0, 0);
}

// ---- fp32 -> bf16 hi/lo split. hi = trunc, lo = RNE(x-hi) ----
__device__ __forceinline__ unsigned bf_rnd(float x) {
    unsigned u = __float_as_uint(x);
    return (u + 0x7FFFu + ((u >> 16) & 1u)) & 0xFFFF0000u;
}
__device__ __forceinline__ void split_bf(float x, unsigned &h, unsigned &l) {
    unsigned hr = bf_rnd(x);
    h = hr >> 16;
    float lo = x - __uint_as_float(hr);
    l = bf_rnd(lo) >> 16;
}
__device__ __forceinline__ void split8q(const f32x4 a, const f32x4 b, bf16x8 &hv, bf16x8 &lv) {
    u32x4 hp, lp;
    #pragma unroll
    for (int i = 0; i < 2; ++i) {
        float x0 = (i ? b : a)[0], x1 = (i ? b : a)[1], x2 = (i ? b : a)[2], x3 = (i ? b : a)[3];
        unsigned h0 = __float_as_uint(x0) & 0xFFFF0000u;
        unsigned h1 = __float_as_uint(x1) & 0xFFFF0000u;
        unsigned h2 = __float_as_uint(x2) & 0xFFFF0000u;
        unsigned h3 = __float_as_uint(x3) & 0xFFFF0000u;
        unsigned l0 = bf_rnd(x0 - __uint_as_float(h0));
        unsigned l1 = bf_rnd(x1 - __uint_as_float(h1));
        unsigned l2 = bf_rnd(x2 - __uint_as_float(h2));
        unsigned l3 = bf_rnd(x3 - __uint_as_float(h3));
        hp[i*2+0] = (h0 >> 16) | h1;  lp[i*2+0] = (l0 >> 16) | l1;
        hp[i*2+1] = (h2 >> 16) | h3;  lp[i*2+1] = (l2 >> 16) | l3;
    }
    hv = __builtin_bit_cast(bf16x8, hp);
    lv = __builtin_bit_cast(bf16x8, lp);
}
__device__ __forceinline__ bf16x8 ld16(const u16* p) {
    return __builtin_bit_cast(bf16x8, *(const u32x4*)p);
}

// =====================================================================
// K0: pre-split weights into FRAGMENT-CONTIGUOUS bf16 hi/lo layout:
// frag F holds a 16(rows)x32(k) MFMA B-operand tile; a wave's ld16 at
// (F*64+lane)*8 u16 is a contiguous 1KB load.
//   We: F = ((f>>6)*4 + ((f>>4)&3))*4 + (e>>5)           (32 frags)
//   Wr: F = (h>>4)*12 + (k>>5)                           (192 frags)
//   W0/W1: F = (h>>4)*8 + (k>>5)                         (128 frags)
// lane = ((k>>3)&3)*16 + (row&15), elem = k&7.
// =====================================================================
__global__ __launch_bounds__(256) void k_prep(
    const float* __restrict__ We, const float* __restrict__ Wr,
    const float* __restrict__ W0, const float* __restrict__ W1,
    u16* __restrict__ WeTh, u16* __restrict__ WeTl,
    u16* __restrict__ WrTh, u16* __restrict__ WrTl,
    u16* __restrict__ W0Th, u16* __restrict__ W0Tl,
    u16* __restrict__ W1Th, u16* __restrict__ W1Tl)
{
    int t = blockIdx.x * 256 + threadIdx.x;
    float v; u16 *dh, *dl; int dst;
    if (t < 16384) {
        int f = t & 127, e = t >> 7;
        v = We[e*128 + f];
        int F = ((f>>6)*4 + ((f>>4)&3))*4 + (e>>5);
        dst = F*512 + (((e>>3)&3)*16 + (f&15))*8 + (e&7);
        dh = WeTh; dl = WeTl;
    } else if (t < 114688) {
        int u = t - 16384; int h = u & 255, k = u >> 8;
        v = Wr[k*256 + h];
        int F = (h>>4)*12 + (k>>5);
        dst = F*512 + (((k>>3)&3)*16 + (h&15))*8 + (k&7);
        dh = WrTh; dl = WrTl;
    } else if (t < 180224) {
        int u = t - 114688; int h = u & 255, k = u >> 8;
        v = W0[k*256 + h];
        int F = (h>>4)*8 + (k>>5);
        dst = F*512 + (((k>>3)&3)*16 + (h&15))*8 + (k&7);
        dh = W0Th; dl = W0Tl;
    } else {
        int u = t - 180224; int h = u & 255, k = u >> 8;
        v = W1[k*256 + h];
        int F = (h>>4)*8 + (k>>5);
        dst = F*512 + (((k>>3)&3)*16 + (h&15))*8 + (k&7);
        dh = W1Th; dl = W1Tl;
    }
    unsigned hh, ll; split_bf(v, hh, ll);
    dh[dst] = (u16)hh; dl[dst] = (u16)ll;
}

// =====================================================================
// K1: fused edge-mapper + msg_e partial reduction, counted-vmcnt pipeline.
// Grid 512 = 16b x 8c(16 i) x 4jh(32 j). Block 256 thr (4 waves: 2j x 2f).
// LDS: 4 x 16KB ring of f32 E slabs (+2KB A). 3 slabs in flight always;
// per slab: s_waitcnt vmcnt(8) + raw s_barrier (never vmcnt(0) in loop).
// W frags (128 VGPR) + A (LDS) preloaded and drained before the pipe.
// =====================================================================
__device__ __forceinline__ void stage_slab(const float* __restrict__ Eslab,
                                           float* buf, int tid) {
    const int w = tid >> 6, l = tid & 63;
    #pragma unroll
    for (int r = 0; r < 4; ++r) {
        const int q   = (r << 2) + w;                 // 1KB chunk 0..15
        const int row = (q << 1) + (l >> 5);          // 0..31
        const int c   = ((l & 31) ^ (row & 7)) << 2;  // swizzled f32 col
        gld16(Eslab + row*128 + c, buf + (q << 8));
    }
}

__global__ __launch_bounds__(256) __attribute__((amdgpu_waves_per_eu(2, 2)))
void k_edge(
    const float* __restrict__ E, const float* __restrict__ A,
    const u16* __restrict__ WeTh, const u16* __restrict__ WeTl,
    const float* __restrict__ be, float* __restrict__ part)
{
    __shared__ __align__(16) float sEf[4*4096];   // 64 KB ring
    __shared__ __align__(16) float sA[512];       // A[16 i][32 j]

    const int tid  = threadIdx.x;
    const int lane = tid & 63;
    const int wv   = tid >> 6;
    const int lrow = lane & 15;
    const int lk   = lane >> 4;
    const int wm   = (wv >> 1) << 4;   // j-offset: 0/16
    const int wn   = (wv & 1)  << 6;   // f-offset: 0/64
    const int bid  = blockIdx.x;
    const int jh   = bid & 3;
    const int c    = (bid >> 2) & 7;
    const int b    = bid >> 5;
    const int i0   = c << 4;
    const int j0   = jh << 5;

    // ---- preload A tile into LDS + be into regs (vmem drained below) ----
    #pragma unroll
    for (int q = 0; q < 2; ++q) {
        const int idx = q*256 + tid;
        sA[idx] = A[(size_t)(b*128 + i0 + (idx >> 5))*128 + j0 + (idx & 31)];
    }
    float ber[4];
    #pragma unroll
    for (int n = 0; n < 4; ++n) ber[n] = be[wn + n*16 + lrow];

    // ---- W fragments resident in registers (frag-contiguous loads) ----
    bf16x8 wh[4][4], wl[4][4];
    {
        const int F0 = (wv & 1) * 16;   // wnIdx*4*4
        #pragma unroll
        for (int n = 0; n < 4; ++n)
            #pragma unroll
            for (int k = 0; k < 4; ++k) {
                const int off = (F0 + n*4 + k)*512 + lane*8;
                wh[n][k] = ld16(WeTh + off);
                wl[n][k] = ld16(WeTl + off);
            }
    }
    // drain everything so loop-entry outstanding == stage ops only
    asm volatile("s_waitcnt vmcnt(0) lgkmcnt(0)" ::: "memory");

    const float* Eb = E + ((size_t)((b*128 + i0)*128 + j0)) * 128;
    stage_slab(Eb,            sEf,          tid);   // slab 0
    stage_slab(Eb + 16384,    sEf + 4096,   tid);   // slab 1
    stage_slab(Eb + 2*16384,  sEf + 2*4096, tid);   // slab 2

    f32x4 P[4] = {};   // msg_e partials [n], lives whole loop

#define EDGE_STEP(S, NWs)                                                    \
    {                                                                        \
        asm volatile("s_waitcnt vmcnt(" NWs ")" ::: "memory");               \
        __builtin_amdgcn_s_barrier();                                        \
        __builtin_amdgcn_sched_barrier(0);                                   \
        if ((S) < 13)                                                        \
            stage_slab(Eb + (size_t)((S)+3)*16384,                           \
                       sEf + (((S)+3) & 3)*4096, tid);                       \
        const char* buf = (const char*)(sEf + ((S) & 3)*4096);               \
        const int jr = wm + lrow;                                            \
        const int sw = (jr & 7) << 4;                                        \
        f32x4 em[4] = {};                                                    \
        _Pragma("unroll")                                                    \
        for (int k = 0; k < 4; ++k) {                                        \
            const int cb = k*128 + lk*32;                                    \
            const f32x4 e0 = *(const f32x4*)(buf + jr*512 + ((cb +  0)^sw)); \
            const f32x4 e1 = *(const f32x4*)(buf + jr*512 + ((cb + 16)^sw)); \
            bf16x8 eh, el; split8q(e0, e1, eh, el);                          \
            _Pragma("unroll")                                                \
            for (int n = 0; n < 4; ++n) {                                    \
                em[n] = MFMA16(eh, wh[n][k], em[n]);                         \
                em[n] = MFMA16(eh, wl[n][k], em[n]);                         \
                em[n] = MFMA16(el, wh[n][k], em[n]);                         \
            }                                                                \
        }                                                                    \
        const f32x4 a4 = *(const f32x4*)(sA + (S)*32 + wm + lk*4);           \
        _Pragma("unroll")                                                    \
        for (int n = 0; n < 4; ++n)                                          \
            _Pragma("unroll")                                                \
            for (int r = 0; r < 4; ++r) {                                    \
                float v = fmaxf(em[n][r] + ber[n], 0.0f);                    \
                P[n][r] += a4[r] * v;                                        \
            }                                                                \
    }

    EDGE_STEP(0,  "8")  EDGE_STEP(1,  "8")  EDGE_STEP(2,  "8")
    EDGE_STEP(3,  "8")  EDGE_STEP(4,  "8")  EDGE_STEP(5,  "8")
    EDGE_STEP(6,  "8")  EDGE_STEP(7,  "8")  EDGE_STEP(8,  "8")
    EDGE_STEP(9,  "8")  EDGE_STEP(10, "8")  EDGE_STEP(11, "8")
    EDGE_STEP(12, "8")  EDGE_STEP(13, "8")  EDGE_STEP(14, "4")
    EDGE_STEP(15, "0")
#undef EDGE_STEP

    // partial tile: part[bid][32 j][128 f]
    float* op = part + (size_t)bid * 4096;
    #pragma unroll
    for (int r = 0; r < 4; ++r) {
        const int j = wm + lk*4 + r;
        #pragma unroll
        for (int n = 0; n < 4; ++n)
            op[j*128 + wn + n*16 + lrow] = P[n][r];
    }
}

// =====================================================================
// K2 (role-split, grid 512): blocks 0..255 reduce msg_e partials (8 chunks),
// blocks 256..511 compute msg_x = A^T X. Output msg pre-split bf16 hi/lo.
// =====================================================================
__global__ __launch_bounds__(256) void k_msg(
    const float* __restrict__ A, const float* __restrict__ X,
    const float* __restrict__ part,
    u16* __restrict__ msg_h, u16* __restrict__ msg_l)
{
    const int bid = blockIdx.x;
    const int tid = threadIdx.x;
    __shared__ float sAt[128*8];

    if (bid < 256) {
        const int b = bid >> 4, jt = bid & 15;
        #pragma unroll
        for (int q = 0; q < 4; ++q) {
            const int e   = (q << 8) + tid;
            const int row = jt*8 + (e >> 7);   // global j
            const int f   = e & 127;
            const float* p = part + ((size_t)b*32 + (row >> 5))*4096
                                  + (row & 31)*128 + f;
            float ssum = 0.f;
            #pragma unroll
            for (int cc = 0; cc < 8; ++cc) ssum += p[(size_t)cc*16384];
            unsigned hh, ll; split_bf(ssum, hh, ll);
            const size_t o = (size_t)(b*128 + row)*384 + 256 + f;
            msg_h[o] = (u16)hh; msg_l[o] = (u16)ll;
        }
    } else {
        const int idx = bid - 256;
        const int b = idx >> 4, jt = idx & 15, j0 = jt << 3;
        #pragma unroll
        for (int q = 0; q < 4; ++q) {
            const int e = tid + q*256;
            sAt[e] = A[(size_t)(b*128 + (e >> 3))*128 + j0 + (e & 7)];
        }
        __syncthreads();
        const int h = tid;
        float acc[8] = {};
        const float* Xb = X + (size_t)b*32768 + h;
        #pragma unroll 2
        for (int i = 0; i < 128; ++i) {
            const float x  = Xb[(size_t)i*256];
            const f32x4 a0 = *(const f32x4*)(sAt + i*8);
            const f32x4 a1 = *(const f32x4*)(sAt + i*8 + 4);
            acc[0] += a0[0]*x; acc[1] += a0[1]*x; acc[2] += a0[2]*x; acc[3] += a0[3]*x;
            acc[4] += a1[0]*x; acc[5] += a1[1]*x; acc[6] += a1[2]*x; acc[7] += a1[3]*x;
        }
        #pragma unroll
        for (int jj = 0; jj < 8; ++jj) {
            unsigned hh, ll; split_bf(acc[jj], hh, ll);
            const size_t o = (size_t)(b*128 + j0 + jj)*384 + h;
            msg_h[o] = (u16)hh; msg_l[o] = (u16)ll;
        }
    }
}

// =====================================================================
// K3/K4/K5: tail GEMM, pure-register MFMA. B in fragment-contiguous layout.
// out(2048x256) = [ (1+eps)*res + ] relu(In(2048xKT) @ W(KTx256) + bias)
// =====================================================================
template<int KT, bool RES, bool F32OUT>
__global__ __launch_bounds__(256) void k_tail(
    const u16* __restrict__ Ah, const u16* __restrict__ Al,
    const u16* __restrict__ Bh, const u16* __restrict__ Bl,
    const float* __restrict__ bias, const float* __restrict__ res,
    const float* __restrict__ epsp,
    float* __restrict__ outf, u16* __restrict__ oh, u16* __restrict__ ol)
{
    constexpr int NB = KT/32;
    const int tid  = threadIdx.x;
    const int lane = tid & 63;
    const int wid  = tid >> 6;
    const int lrow = lane & 15;
    const int lk   = lane >> 4;
    const int wm   = (wid >> 1) << 4;
    const int wn   = (wid & 1)  << 5;
    const int r0   = blockIdx.x << 5;
    const int h0   = blockIdx.y << 6;

    const int arow = r0 + wm + lrow;
    const u16* pah = Ah + (size_t)arow*KT + lk*8;
    const u16* pal = Al + (size_t)arow*KT + lk*8;
    const size_t bb = (size_t)((h0 + wn) >> 4) * NB * 512 + lane*8;
    const u16* pbh = Bh + bb;
    const u16* pbl = Bl + bb;

    f32x4 P[2] = {};
    #pragma unroll
    for (int ks = 0; ks < NB; ++ks) {
        const bf16x8 ah  = ld16(pah + ks*32);
        const bf16x8 al  = ld16(pal + ks*32);
        const bf16x8 b0h = ld16(pbh + ks*512), b0l = ld16(pbl + ks*512);
        const bf16x8 b1h = ld16(pbh + (NB + ks)*512), b1l = ld16(pbl + (NB + ks)*512);
        P[0] = MFMA16(ah, b0h, P[0]);
        P[0] = MFMA16(ah, b0l, P[0]);
        P[0] = MFMA16(al, b0h, P[0]);
        P[1] = MFMA16(ah, b1h, P[1]);
        P[1] = MFMA16(ah, b1l, P[1]);
        P[1] = MFMA16(al, b1h, P[1]);
    }

    const float eps = RES ? epsp[0] : 0.f;
    #pragma unroll
    for (int n = 0; n < 2; ++n) {
        const int col = h0 + wn + n*16 + lrow;
        const float bv = bias[col];
        #pragma unroll
        for (int e = 0; e < 4; ++e) {
            const int r = r0 + wm + lk*4 + e;
            float v = fmaxf(P[n][e] + bv, 0.f);
            if (RES) v += (1.f + eps) * res[(size_t)r*256 + col];
            if (F32OUT) {
                outf[(size_t)r*256 + col] = v;
            } else {
                unsigned hh, ll; split_bf(v, hh, ll);
                oh[(size_t)r*256 + col] = (u16)hh;
                ol[(size_t)r*256 + col] = (u16)ll;
            }
        }
    }
}

extern "C" void kernel_launch(void* const* d_in, const int* in_sizes, int n_in,
                              void* d_out, int out_size, void* d_ws, size_t ws_size,
                              hipStream_t stream)
{
    const float* X   = (const float*)d_in[0];
    const float* E   = (const float*)d_in[1];
    const float* A   = (const float*)d_in[2];
    const float* eps = (const float*)d_in[3];
    const float* We  = (const float*)d_in[4];
    const float* be  = (const float*)d_in[5];
    const float* Wr  = (const float*)d_in[6];
    const float* br  = (const float*)d_in[7];
    const float* W0  = (const float*)d_in[8];
    const float* b0  = (const float*)d_in[9];
    const float* W1  = (const float*)d_in[10];
    const float* b1  = (const float*)d_in[11];
    float* out = (float*)d_out;

    u16* w = (u16*)d_ws;
    u16* WeTh = w;              u16* WeTl = WeTh + 16384;
    u16* WrTh = WeTl + 16384;   u16* WrTl = WrTh + 98304;
    u16* W0Th = WrTl + 98304;   u16* W0Tl = W0Th + 65536;
    u16* W1Th = W0Tl + 65536;   u16* W1Tl = W1Th + 65536;
    u16* msg_h = W1Tl + 65536;  u16* msg_l = msg_h + 786432;
    u16* o1h = msg_l + 786432;  u16* o1l = o1h + 524288;
    u16* o2h = o1l + 524288;    u16* o2l = o2h + 524288;
    float* part = (float*)(o2l + 524288);   // 512 * 4096 f32 = 8 MB

    k_prep<<<960, 256, 0, stream>>>(We, Wr, W0, W1,
        WeTh, WeTl, WrTh, WrTl, W0Th, W0Tl, W1Th, W1Tl);
    k_edge<<<512, 256, 0, stream>>>(E, A, WeTh, WeTl, be, part);
    k_msg<<<512, 256, 0, stream>>>(A, X, part, msg_h, msg_l);
    k_tail<384, true , false><<<dim3(64,4), 256, 0, stream>>>(
        msg_h, msg_l, WrTh, WrTl, br, X, eps, nullptr, o1h, o1l);
    k_tail<256, false, false><<<dim3(64,4), 256, 0, stream>>>(
        o1h, o1l, W0Th, W0Tl, b0, nullptr, nullptr, nullptr, o2h, o2l);
    k_tail<256, false, true ><<<dim3(64,4), 256, 0, stream>>>(
        o2h, o2l, W1Th, W1Tl, b1, nullptr, nullptr, out, nullptr, nullptr);
}